// Round 1
// baseline (195.923 us; speedup 1.0000x reference)
//
#include <hip/hip_runtime.h>

// Attention, 20 slices of [N=1024, D=256]. R6: kill the LDS staging.
// Insight: Kmd/Vb tiles had ZERO cross-wave sharing (wave reads only its own
// 16 m-rows / 64 d-cols) -> K,V fragments now load global->VGPR directly from
// bf16 tensors precomputed by prep (XT[n][d] for Q/K, XV[m>>3][d][m&7] so V
// B-frags are contiguous 16B). Only P stays in LDS (double-buffered, 8.8KB)
// -> 3 blocks/CU, all 640 blocks resident, 1 lgkmcnt-only barrier per kt,
// loads pipelined one iteration ahead across the barrier (counted vmcnt via
// register deps, never drained). Prep rewritten as LDS-tile transposes with
// full-line coalesced stores (old prep wrote 16B scatter @1KB stride).

typedef __attribute__((ext_vector_type(8))) short bf16x8;
typedef __attribute__((ext_vector_type(4))) float f32x4;
typedef __attribute__((ext_vector_type(16))) float f32x16;

// per-wave LDS-only barrier: no vmcnt drain (keeps global loads in flight)
#define LDS_BARRIER() __asm__ volatile("s_waitcnt lgkmcnt(0)\ns_barrier" ::: "memory")

__device__ __forceinline__ unsigned int pack_bf16_rne(float a, float b) {
    unsigned int ua = __float_as_uint(a); ua += 0x7FFFu + ((ua >> 16) & 1u);
    unsigned int ub = __float_as_uint(b); ub += 0x7FFFu + ((ub >> 16) & 1u);
    return (ua >> 16) | (ub & 0xFFFF0000u);
}
__device__ __forceinline__ unsigned int pack2_trunc(float lo, float hi) {
    return __builtin_amdgcn_perm(__float_as_uint(hi), __float_as_uint(lo), 0x07060302u);
}

// Fused prep: bid<640 -> XV tiles, else -> XT tiles. x is [slice][d=256][n=1024].
// XT[slice][n][d] bf16 (plain).  XV[slice][cc=m>>3][d][j=m&7] bf16 (16B cells).
__global__ __launch_bounds__(256) void prep_kernel(const float* __restrict__ x,
                                                   unsigned short* __restrict__ XT,
                                                   unsigned short* __restrict__ XV) {
    __shared__ __align__(16) unsigned char smem[16384];
    int bid = blockIdx.x;
    int t = threadIdx.x;
    if (bid < 640) {
        // XV: transpose a 32cc x 32d tile of 16B cells through LDS.
        uint4* T = (uint4*)smem;                      // [32cc][32d'] 16KB
        int slice = bid >> 5, w = bid & 31;
        int cc0 = (w & 3) * 32, d0 = (w >> 2) * 32;
        const float* xs = x + slice * 262144;
        int ccl = t & 31, dr = t >> 5;                // load: lanes->cc (1KB coalesced)
        #pragma unroll
        for (int p = 0; p < 4; ++p) {
            int dl = p * 8 + dr;
            const float* src = xs + (d0 + dl) * 1024 + (cc0 + ccl) * 8;
            float4 a = *(const float4*)(src);
            float4 b = *(const float4*)(src + 4);
            uint4 o;
            o.x = pack_bf16_rne(a.x, a.y); o.y = pack_bf16_rne(a.z, a.w);
            o.z = pack_bf16_rne(b.x, b.y); o.w = pack_bf16_rne(b.z, b.w);
            T[ccl * 32 + (dl ^ ccl)] = o;             // XOR-swizzled cell
        }
        __syncthreads();
        unsigned short* xv = XV + slice * 262144;
        int dl2 = t & 31, cr = t >> 5;                // store: lanes->d (512B segments)
        #pragma unroll
        for (int p = 0; p < 4; ++p) {
            int ccl2 = p * 8 + cr;
            uint4 o = T[ccl2 * 32 + (dl2 ^ ccl2)];
            *(uint4*)(xv + ((cc0 + ccl2) * 256 + d0 + dl2) * 8) = o;
        }
    } else {
        // XT: 128d x 64n tile, 4x4 micro-tile transpose via LDS.
        unsigned long long* TX = (unsigned long long*)smem;   // [64n][32dq] 8B, 16KB
        int b = bid - 640;
        int slice = b >> 5, w = b & 31;
        int d0 = (w & 1) * 128, n0 = (w >> 1) * 64;
        const float* xs = x + slice * 262144;
        int nq = t & 15, dqh = t >> 4;
        #pragma unroll
        for (int p = 0; p < 2; ++p) {
            int dq = p * 16 + dqh;                    // d = d0 + dq*4
            const float* src = xs + (d0 + dq * 4) * 1024 + n0 + nq * 4;
            float4 r0 = *(const float4*)(src);
            float4 r1 = *(const float4*)(src + 1024);
            float4 r2 = *(const float4*)(src + 2048);
            float4 r3 = *(const float4*)(src + 3072);
            const float* f0 = (const float*)&r0; const float* f1 = (const float*)&r1;
            const float* f2 = (const float*)&r2; const float* f3 = (const float*)&r3;
            #pragma unroll
            for (int j = 0; j < 4; ++j) {
                int nl2 = nq * 4 + j;
                unsigned long long q = (unsigned long long)pack_bf16_rne(f0[j], f1[j])
                    | ((unsigned long long)pack_bf16_rne(f2[j], f3[j]) << 32);
                TX[nl2 * 32 + (dq ^ (nl2 & 31))] = q;
            }
        }
        __syncthreads();
        unsigned short* xt = XT + slice * 262144;
        int ch = t & 15, nr = t >> 4;
        #pragma unroll
        for (int p = 0; p < 4; ++p) {
            int nl2 = p * 16 + nr;
            unsigned long long qlo = TX[nl2 * 32 + ((ch * 2) ^ (nl2 & 31))];
            unsigned long long qhi = TX[nl2 * 32 + ((ch * 2 + 1) ^ (nl2 & 31))];
            uint4 o = make_uint4((unsigned int)qlo, (unsigned int)(qlo >> 32),
                                 (unsigned int)qhi, (unsigned int)(qhi >> 32));
            *(uint4*)(xt + (n0 + nl2) * 256 + d0 + ch * 8) = o;   // 256B rows, full lines
        }
    }
}

__global__ __launch_bounds__(256, 3) void attn_kernel(const unsigned short* __restrict__ XT,
                                                      const unsigned short* __restrict__ XV,
                                                      const int* __restrict__ beta,
                                                      float* __restrict__ out) {
    __shared__ __align__(16) unsigned short Pb[2][32 * 64];   // P dbuf, 8KB total
    __shared__ float Lpart[4 * 32];
    __shared__ __align__(16) float Ltot[32];

    int bid = blockIdx.x;
    int t = ((bid & 7) * 80) + (bid >> 3);      // XCD-locality swizzle (640 blocks)
    int slice = t >> 5, qh = t & 31;

    int tid = threadIdx.x;
    int lane = tid & 63, wv = tid >> 6;
    int nl = lane & 15, g = lane >> 4;          // 16x16 frame
    int lo = lane & 31, hi = lane >> 5;         // 32x32 frame

    const unsigned short* xt_s = XT + slice * 262144;
    const unsigned short* xv_s = XV + slice * 262144;
    float cscale = (float)(beta[0]) * 1.44269504089f;   // beta * log2(e)

    // ---- Q fragments (2 strips of 16 n) + fixed softmax max per column ----
    bf16x8 qf[2][8];
    float mcol[2];
    #pragma unroll
    for (int nq = 0; nq < 2; ++nq) {
        int n = qh * 32 + nq * 16 + nl;
        const unsigned short* qrow = xt_s + n * 256;
        float dg = 0.f;
        #pragma unroll
        for (int ks = 0; ks < 8; ++ks) {
            qf[nq][ks] = *(const bf16x8*)(qrow + (ks * 4 + g) * 8);
            const unsigned int* qu = (const unsigned int*)&qf[nq][ks];
            #pragma unroll
            for (int w = 0; w < 4; ++w) {
                float flo = __uint_as_float(qu[w] << 16);
                float fhi = __uint_as_float(qu[w] & 0xFFFF0000u);
                dg = fmaf(flo, flo, dg);
                dg = fmaf(fhi, fhi, dg);
            }
        }
        dg += __shfl_xor(dg, 16);
        dg += __shfl_xor(dg, 32);
        mcol[nq] = dg * cscale;
    }

    f32x16 acc[2];                   // O[32n x 64d]: wave owns d in [wv*64,+64)
    acc[0] = (f32x16)(0.f); acc[1] = (f32x16)(0.f);
    float lac0 = 0.f, lac1 = 0.f;

    bf16x8 af[8], vf[8];
    // af(kt,ks) = XT[kt*64 + wv*16 + nl][(ks*4+g)*8 ..]
    const unsigned short* kb = xt_s + (wv * 16 + nl) * 256 + g * 8;
    // vf(kt,ks,db) = XV cell (cc = kt*8 + ks*2 + hi, d = wv*64 + db*32 + lo)
    const unsigned short* vb = xv_s + (hi * 256 + wv * 64 + lo) * 8;

    // S + softmax + P write for current af/qf -> Pb[pbi]
    auto S_phase = [&](int pbi) {
        f32x4 s0 = {0.f,0.f,0.f,0.f}, s1 = {0.f,0.f,0.f,0.f};
        #pragma unroll
        for (int ks = 0; ks < 8; ++ks) {
            s0 = __builtin_amdgcn_mfma_f32_16x16x32_bf16(af[ks], qf[0][ks], s0, 0, 0, 0);
            s1 = __builtin_amdgcn_mfma_f32_16x16x32_bf16(af[ks], qf[1][ks], s1, 0, 0, 0);
        }
        {
            float p0 = exp2f(fmaf(s0[0], cscale, -mcol[0]));
            float p1 = exp2f(fmaf(s0[1], cscale, -mcol[0]));
            float p2 = exp2f(fmaf(s0[2], cscale, -mcol[0]));
            float p3 = exp2f(fmaf(s0[3], cscale, -mcol[0]));
            lac0 += (p0 + p1) + (p2 + p3);
            *(uint2*)(&Pb[pbi][nl * 64 + (((wv * 2 + (g >> 1)) ^ (nl & 7)) * 8) + (g & 1) * 4]) =
                make_uint2(pack2_trunc(p0, p1), pack2_trunc(p2, p3));
        }
        {
            float p0 = exp2f(fmaf(s1[0], cscale, -mcol[1]));
            float p1 = exp2f(fmaf(s1[1], cscale, -mcol[1]));
            float p2 = exp2f(fmaf(s1[2], cscale, -mcol[1]));
            float p3 = exp2f(fmaf(s1[3], cscale, -mcol[1]));
            lac1 += (p0 + p1) + (p2 + p3);
            *(uint2*)(&Pb[pbi][(16 + nl) * 64 + (((wv * 2 + (g >> 1)) ^ (nl & 7)) * 8) + (g & 1) * 4]) =
                make_uint2(pack2_trunc(p0, p1), pack2_trunc(p2, p3));
        }
    };

    // ---- prologue: af(0), vf(0), S(0), issue af(1) ----
    #pragma unroll
    for (int ks = 0; ks < 8; ++ks) af[ks] = *(const bf16x8*)(kb + ks * 32);
    #pragma unroll
    for (int ks = 0; ks < 4; ++ks) {
        vf[ks * 2]     = *(const bf16x8*)(vb + ks * 4096);
        vf[ks * 2 + 1] = *(const bf16x8*)(vb + ks * 4096 + 256);
    }
    S_phase(0);
    #pragma unroll
    for (int ks = 0; ks < 8; ++ks) af[ks] = *(const bf16x8*)(kb + 16384 + ks * 32);
    LDS_BARRIER();

    for (int kt = 1; kt < 16; ++kt) {
        int pb = (kt - 1) & 1;
        // ---- PV(kt-1): O += P[32n x 64m] * V[64m x 64d], 32x32x16, vf in regs ----
        #pragma unroll
        for (int ks = 0; ks < 4; ++ks) {
            bf16x8 pf = *(const bf16x8*)(&Pb[pb][lo * 64 + (((ks * 2 + hi) ^ (lo & 7)) * 8)]);
            acc[0] = __builtin_amdgcn_mfma_f32_32x32x16_bf16(pf, vf[ks * 2],     acc[0], 0, 0, 0);
            acc[1] = __builtin_amdgcn_mfma_f32_32x32x16_bf16(pf, vf[ks * 2 + 1], acc[1], 0, 0, 0);
        }
        // issue vf(kt): consumed at PV(kt) next iteration (hides under S+barrier)
        {
            const unsigned short* vkt = vb + kt * 16384;
            #pragma unroll
            for (int ks = 0; ks < 4; ++ks) {
                vf[ks * 2]     = *(const bf16x8*)(vkt + ks * 4096);
                vf[ks * 2 + 1] = *(const bf16x8*)(vkt + ks * 4096 + 256);
            }
        }
        // ---- S(kt) on af(kt) (issued last iteration; waits vmcnt(8), vf stays in flight)
        S_phase(kt & 1);
        // issue af(kt+1): consumed at S(kt+1) (hides under barrier+PV)
        if (kt < 15) {
            const unsigned short* kkt = kb + (kt + 1) * 16384;
            #pragma unroll
            for (int ks = 0; ks < 8; ++ks) af[ks] = *(const bf16x8*)(kkt + ks * 32);
        }
        LDS_BARRIER();               // lgkmcnt-only: P(kt) visible, global loads in flight
    }
    // ---- PV(15) ----
    #pragma unroll
    for (int ks = 0; ks < 4; ++ks) {
        bf16x8 pf = *(const bf16x8*)(&Pb[1][lo * 64 + (((ks * 2 + hi) ^ (lo & 7)) * 8)]);
        acc[0] = __builtin_amdgcn_mfma_f32_32x32x16_bf16(pf, vf[ks * 2],     acc[0], 0, 0, 0);
        acc[1] = __builtin_amdgcn_mfma_f32_32x32x16_bf16(pf, vf[ks * 2 + 1], acc[1], 0, 0, 0);
    }

    // ---- epilogue: softmax denominators, scale, store ----
    lac0 += __shfl_xor(lac0, 16); lac0 += __shfl_xor(lac0, 32);
    lac1 += __shfl_xor(lac1, 16); lac1 += __shfl_xor(lac1, 32);
    if (lane < 16) {
        Lpart[wv * 32 + nl] = lac0;
        Lpart[wv * 32 + 16 + nl] = lac1;
    }
    LDS_BARRIER();
    if (tid < 32)
        Ltot[tid] = 1.f / (Lpart[tid] + Lpart[32 + tid] + Lpart[64 + tid] + Lpart[96 + tid]);
    LDS_BARRIER();

    float* outs = out + slice * 262144 + (qh * 32) * 256;
    #pragma unroll
    for (int rq = 0; rq < 4; ++rq) {
        f32x4 li = *(const f32x4*)(&Ltot[rq * 8 + hi * 4]);
        #pragma unroll
        for (int j = 0; j < 4; ++j) {
            int nloc = rq * 8 + hi * 4 + j;
            #pragma unroll
            for (int db = 0; db < 2; ++db)
                outs[nloc * 256 + wv * 64 + db * 32 + lo] = acc[db][rq * 4 + j] * li[j];
        }
    }
}

extern "C" void kernel_launch(void* const* d_in, const int* in_sizes, int n_in,
                              void* d_out, int out_size, void* d_ws, size_t ws_size,
                              hipStream_t stream) {
    const float* x = (const float*)d_in[0];
    const int* beta = (const int*)d_in[1];
    float* out = (float*)d_out;
    unsigned short* XT = (unsigned short*)d_ws;                 // 10,485,760 B
    unsigned short* XV = (unsigned short*)d_ws + 5242880;       // 10,485,760 B (ws total ~21MB)
    prep_kernel<<<1280, 256, 0, stream>>>(x, XT, XV);
    attn_kernel<<<640, 256, 0, stream>>>(XT, XV, beta, out);
}

// Round 2
// 115.692 us; speedup vs baseline: 1.6935x; 1.6935x over previous
//
#include <hip/hip_runtime.h>

// Attention, 20 slices of [N=1024, D=256]. R7: K via LDS-DMA (0 VGPRs), V via
// direct bf16 reg loads from XV (R6-verified), P double-buffered in LDS.
// Per-wave Kmd self-staging (wave reads only rows it DMA'd) -> K needs NO
// barrier, only a counted per-wave s_waitcnt vmcnt(8) (vf loads stay in
// flight). ONE lgkmcnt-only barrier per kt (R5 had 3, incl. a vmcnt(0)
// drain). No fp32 V load/repack. launch_bounds(256,2): reg cap 256 ->
// guaranteed no spill (R6 spilled ~29MB/iter under the (256,3) 128-reg cap).

typedef __attribute__((ext_vector_type(8))) short bf16x8;
typedef __attribute__((ext_vector_type(4))) float f32x4;
typedef __attribute__((ext_vector_type(16))) float f32x16;

#define GLD16(gp, lp) __builtin_amdgcn_global_load_lds( \
    (const __attribute__((address_space(1))) unsigned int*)(const void*)(gp), \
    (__attribute__((address_space(3))) unsigned int*)(void*)(lp), 16, 0, 0)

// LDS-only barrier: no vmcnt drain (K-DMA + vf global loads stay in flight)
#define LDS_BARRIER() __asm__ volatile("s_waitcnt lgkmcnt(0)\ns_barrier" ::: "memory")
#define MEMFENCE()    __asm__ volatile("" ::: "memory")
// wait for the 8 oldest VMEM ops (this wave's K-DMA); 8 newer vf loads keep flying
#define WAIT_KDMA()   do { __asm__ volatile("s_waitcnt vmcnt(8)" ::: "memory"); \
                           __builtin_amdgcn_sched_barrier(0); } while (0)

__device__ __forceinline__ unsigned int pack_bf16_rne(float a, float b) {
    unsigned int ua = __float_as_uint(a); ua += 0x7FFFu + ((ua >> 16) & 1u);
    unsigned int ub = __float_as_uint(b); ub += 0x7FFFu + ((ub >> 16) & 1u);
    return (ua >> 16) | (ub & 0xFFFF0000u);
}
__device__ __forceinline__ unsigned int pack2_trunc(float lo, float hi) {
    return __builtin_amdgcn_perm(__float_as_uint(hi), __float_as_uint(lo), 0x07060302u);
}

// Fused prep: bid<640 -> XV tiles, else -> XT tiles. x is [slice][d=256][n=1024].
// XT[slice][n][chunk^(n&7)] bf16 (16B-chunk XOR swizzle, for conflict-free Kmd
// ds_reads).  XV[slice][cc=m>>3][d][j=m&7] bf16 (16B cells, V B-frags contig).
__global__ __launch_bounds__(256) void prep_kernel(const float* __restrict__ x,
                                                   unsigned short* __restrict__ XT,
                                                   unsigned short* __restrict__ XV) {
    __shared__ __align__(16) unsigned char smem[16384];
    int bid = blockIdx.x;
    int t = threadIdx.x;
    if (bid < 640) {
        // XV: transpose a 32cc x 32d tile of 16B cells through LDS.
        uint4* T = (uint4*)smem;                      // [32cc][32d'] 16KB
        int slice = bid >> 5, w = bid & 31;
        int cc0 = (w & 3) * 32, d0 = (w >> 2) * 32;
        const float* xs = x + slice * 262144;
        int ccl = t & 31, dr = t >> 5;                // load: lanes->cc (1KB coalesced)
        #pragma unroll
        for (int p = 0; p < 4; ++p) {
            int dl = p * 8 + dr;
            const float* src = xs + (d0 + dl) * 1024 + (cc0 + ccl) * 8;
            float4 a = *(const float4*)(src);
            float4 b = *(const float4*)(src + 4);
            uint4 o;
            o.x = pack_bf16_rne(a.x, a.y); o.y = pack_bf16_rne(a.z, a.w);
            o.z = pack_bf16_rne(b.x, b.y); o.w = pack_bf16_rne(b.z, b.w);
            T[ccl * 32 + (dl ^ ccl)] = o;             // XOR-swizzled cell
        }
        __syncthreads();
        unsigned short* xv = XV + slice * 262144;
        int dl2 = t & 31, cr = t >> 5;                // store: lanes->d (512B segments)
        #pragma unroll
        for (int p = 0; p < 4; ++p) {
            int ccl2 = p * 8 + cr;
            uint4 o = T[ccl2 * 32 + (dl2 ^ ccl2)];
            *(uint4*)(xv + ((cc0 + ccl2) * 256 + d0 + dl2) * 8) = o;
        }
    } else {
        // XT: 128d x 64n tile, 4x4 micro-tile transpose via LDS.
        unsigned long long* TX = (unsigned long long*)smem;   // [64n][32dq] 8B, 16KB
        int b = bid - 640;
        int slice = b >> 5, w = b & 31;
        int d0 = (w & 1) * 128, n0 = (w >> 1) * 64;
        const float* xs = x + slice * 262144;
        int nq = t & 15, dqh = t >> 4;
        #pragma unroll
        for (int p = 0; p < 2; ++p) {
            int dq = p * 16 + dqh;                    // d = d0 + dq*4
            const float* src = xs + (d0 + dq * 4) * 1024 + n0 + nq * 4;
            float4 r0 = *(const float4*)(src);
            float4 r1 = *(const float4*)(src + 1024);
            float4 r2 = *(const float4*)(src + 2048);
            float4 r3 = *(const float4*)(src + 3072);
            const float* f0 = (const float*)&r0; const float* f1 = (const float*)&r1;
            const float* f2 = (const float*)&r2; const float* f3 = (const float*)&r3;
            #pragma unroll
            for (int j = 0; j < 4; ++j) {
                int nl2 = nq * 4 + j;
                unsigned long long q = (unsigned long long)pack_bf16_rne(f0[j], f1[j])
                    | ((unsigned long long)pack_bf16_rne(f2[j], f3[j]) << 32);
                TX[nl2 * 32 + (dq ^ (nl2 & 31))] = q;
            }
        }
        __syncthreads();
        unsigned short* xt = XT + slice * 262144;
        int ch = t & 15, nr = t >> 4;
        #pragma unroll
        for (int p = 0; p < 4; ++p) {
            int nl2 = p * 16 + nr;
            unsigned long long qlo = TX[nl2 * 32 + ((ch * 2) ^ (nl2 & 31))];
            unsigned long long qhi = TX[nl2 * 32 + ((ch * 2 + 1) ^ (nl2 & 31))];
            uint4 o = make_uint4((unsigned int)qlo, (unsigned int)(qlo >> 32),
                                 (unsigned int)qhi, (unsigned int)(qhi >> 32));
            // chunk index = (d0>>3)+ch, stored at chunk^(n&7) (Kmd read swizzle)
            *(uint4*)(xt + (n0 + nl2) * 256 + ((((d0 >> 3) + ch) ^ (nl2 & 7)) * 8)) = o;
        }
    }
}

__global__ __launch_bounds__(256, 2) void attn_kernel(const unsigned short* __restrict__ XT,
                                                      const unsigned short* __restrict__ XV,
                                                      const int* __restrict__ beta,
                                                      float* __restrict__ out) {
    __shared__ __align__(16) unsigned short Kmd[64 * 256];    // 32KB K-tile [m][chunk^swz]
    __shared__ __align__(16) unsigned short Pb[2][32 * 64];   // P dbuf, 8KB
    __shared__ float Lpart[4 * 32];
    __shared__ __align__(16) float Ltot[32];

    int bid = blockIdx.x;
    int t = ((bid & 7) * 80) + (bid >> 3);      // XCD-locality swizzle (640 blocks)
    int slice = t >> 5, qh = t & 31;

    int tid = threadIdx.x;
    int lane = tid & 63, wv = tid >> 6;
    int nl = lane & 15, g = lane >> 4;          // 16x16 frame
    int lo = lane & 31, hi = lane >> 5;         // 32x32 frame

    const unsigned short* xt_s = XT + slice * 262144;
    const unsigned short* xv_s = XV + slice * 262144;
    float cscale = (float)(beta[0]) * 1.44269504089f;   // beta * log2(e)

    // ---- prologue: issue K-DMA(0) FIRST (oldest in vm queue) ----
    #pragma unroll
    for (int i = 0; i < 8; ++i) {
        int ch = wv * 8 + i;
        GLD16(xt_s + ch * 512 + lane * 8, &Kmd[ch * 512]);
    }
    MEMFENCE();   // keep qf/vf loads AFTER the DMA issues in the vm queue

    // ---- Q fragments (2 strips of 16 n) + fixed softmax max per column ----
    bf16x8 qf[2][8];
    float mcol[2];
    #pragma unroll
    for (int nq = 0; nq < 2; ++nq) {
        int n = qh * 32 + nq * 16 + nl;
        const unsigned short* qrow = xt_s + n * 256;
        float dg = 0.f;
        #pragma unroll
        for (int ks = 0; ks < 8; ++ks) {
            qf[nq][ks] = *(const bf16x8*)(qrow + (((ks * 4 + g) ^ (n & 7)) * 8));
            const unsigned int* qu = (const unsigned int*)&qf[nq][ks];
            #pragma unroll
            for (int w = 0; w < 4; ++w) {
                float flo = __uint_as_float(qu[w] << 16);
                float fhi = __uint_as_float(qu[w] & 0xFFFF0000u);
                dg = fmaf(flo, flo, dg);
                dg = fmaf(fhi, fhi, dg);
            }
        }
        dg += __shfl_xor(dg, 16);
        dg += __shfl_xor(dg, 32);
        mcol[nq] = dg * cscale;   // consumes all qf loads -> they retire here
    }

    f32x16 acc[2];                   // O[32n x 64d]: wave owns d in [wv*64,+64)
    acc[0] = (f32x16)(0.f); acc[1] = (f32x16)(0.f);
    float lac0 = 0.f, lac1 = 0.f;

    // vf(kt,ks,db) = XV cell (cc = kt*8 + ks*2 + hi, d = wv*64 + db*32 + lo)
    const unsigned short* vb = xv_s + (hi * 256 + wv * 64 + lo) * 8;
    bf16x8 vf[8];
    MEMFENCE();   // vf(0) loads stay after K-DMA(0) in issue order
    #pragma unroll
    for (int ks = 0; ks < 4; ++ks) {
        vf[ks * 2]     = *(const bf16x8*)(vb + ks * 4096);
        vf[ks * 2 + 1] = *(const bf16x8*)(vb + ks * 4096 + 256);
    }
    // vm queue now: [K-DMA(0) x8 oldest][vf(0) x8 newest] = 16 outstanding

    const unsigned short* kmd_row = &Kmd[(wv * 16 + nl) * 256];

    for (int kt = 0; kt < 16; ++kt) {
        WAIT_KDMA();                 // vmcnt(8): Kmd(kt) landed; vf(kt) still flying

        // ---- S(kt): wave's own 16m rows x both 16n strips (A-frag reused) ----
        f32x4 s0 = {0.f,0.f,0.f,0.f}, s1 = {0.f,0.f,0.f,0.f};
        #pragma unroll
        for (int ks = 0; ks < 8; ++ks) {
            bf16x8 af = *(const bf16x8*)(kmd_row + (((ks * 4 + g) ^ (nl & 7)) * 8));
            s0 = __builtin_amdgcn_mfma_f32_16x16x32_bf16(af, qf[0][ks], s0, 0, 0, 0);
            s1 = __builtin_amdgcn_mfma_f32_16x16x32_bf16(af, qf[1][ks], s1, 0, 0, 0);
        }

        // ---- softmax (fixed max) + P write -> Pb[kt&1] ----
        {
            float p0 = exp2f(fmaf(s0[0], cscale, -mcol[0]));
            float p1 = exp2f(fmaf(s0[1], cscale, -mcol[0]));
            float p2 = exp2f(fmaf(s0[2], cscale, -mcol[0]));
            float p3 = exp2f(fmaf(s0[3], cscale, -mcol[0]));
            lac0 += (p0 + p1) + (p2 + p3);
            *(uint2*)(&Pb[kt & 1][nl * 64 + (((wv * 2 + (g >> 1)) ^ (nl & 7)) * 8) + (g & 1) * 4]) =
                make_uint2(pack2_trunc(p0, p1), pack2_trunc(p2, p3));
        }
        {
            float p0 = exp2f(fmaf(s1[0], cscale, -mcol[1]));
            float p1 = exp2f(fmaf(s1[1], cscale, -mcol[1]));
            float p2 = exp2f(fmaf(s1[2], cscale, -mcol[1]));
            float p3 = exp2f(fmaf(s1[3], cscale, -mcol[1]));
            lac1 += (p0 + p1) + (p2 + p3);
            *(uint2*)(&Pb[kt & 1][(16 + nl) * 64 + (((wv * 2 + (g >> 1)) ^ (nl & 7)) * 8) + (g & 1) * 4]) =
                make_uint2(pack2_trunc(p0, p1), pack2_trunc(p2, p3));
        }

        // restage own Kmd rows for kt+1 (af reads already consumed by MFMAs)
        if (kt < 15) {
            const unsigned short* gk = xt_s + (kt + 1) * 16384;
            #pragma unroll
            for (int i = 0; i < 8; ++i) {
                int ch = wv * 8 + i;
                GLD16(gk + ch * 512 + lane * 8, &Kmd[ch * 512]);
            }
        }

        LDS_BARRIER();               // the ONLY barrier per kt: P(kt) visible to all

        // ---- PV(kt): O += P[32n x 64m] * V[64m x 64d], vf in regs; reload vf(kt+1)
        {
            const unsigned short* vnext = vb + (kt + 1) * 16384;
            #pragma unroll
            for (int ks = 0; ks < 4; ++ks) {
                bf16x8 pf = *(const bf16x8*)(&Pb[kt & 1][lo * 64 + (((ks * 2 + hi) ^ (lo & 7)) * 8)]);
                acc[0] = __builtin_amdgcn_mfma_f32_32x32x16_bf16(pf, vf[ks * 2],     acc[0], 0, 0, 0);
                acc[1] = __builtin_amdgcn_mfma_f32_32x32x16_bf16(pf, vf[ks * 2 + 1], acc[1], 0, 0, 0);
                if (kt < 15) {
                    vf[ks * 2]     = *(const bf16x8*)(vnext + ks * 4096);
                    vf[ks * 2 + 1] = *(const bf16x8*)(vnext + ks * 4096 + 256);
                }
            }
        }
        // vm queue at loop top: [K-DMA(kt+1) x8 oldest][vf(kt+1) x8] = 16
    }

    // ---- epilogue: softmax denominators, scale, store ----
    lac0 += __shfl_xor(lac0, 16); lac0 += __shfl_xor(lac0, 32);
    lac1 += __shfl_xor(lac1, 16); lac1 += __shfl_xor(lac1, 32);
    if (lane < 16) {
        Lpart[wv * 32 + nl] = lac0;
        Lpart[wv * 32 + 16 + nl] = lac1;
    }
    LDS_BARRIER();
    if (tid < 32)
        Ltot[tid] = 1.f / (Lpart[tid] + Lpart[32 + tid] + Lpart[64 + tid] + Lpart[96 + tid]);
    LDS_BARRIER();

    float* outs = out + slice * 262144 + (qh * 32) * 256;
    #pragma unroll
    for (int rq = 0; rq < 4; ++rq) {
        f32x4 li = *(const f32x4*)(&Ltot[rq * 8 + hi * 4]);
        #pragma unroll
        for (int j = 0; j < 4; ++j) {
            int nloc = rq * 8 + hi * 4 + j;
            #pragma unroll
            for (int db = 0; db < 2; ++db)
                outs[nloc * 256 + wv * 64 + db * 32 + lo] = acc[db][rq * 4 + j] * li[j];
        }
    }
}

extern "C" void kernel_launch(void* const* d_in, const int* in_sizes, int n_in,
                              void* d_out, int out_size, void* d_ws, size_t ws_size,
                              hipStream_t stream) {
    const float* x = (const float*)d_in[0];
    const int* beta = (const int*)d_in[1];
    float* out = (float*)d_out;
    unsigned short* XT = (unsigned short*)d_ws;                 // 10,485,760 B
    unsigned short* XV = (unsigned short*)d_ws + 5242880;       // 10,485,760 B
    prep_kernel<<<1280, 256, 0, stream>>>(x, XT, XV);
    attn_kernel<<<640, 256, 0, stream>>>(XT, XV, beta, out);
}